// Round 20
// baseline (873.338 us; speedup 1.0000x reference)
//
#include <hip/hip_runtime.h>

#define WS_ALIGN(x) (((x) + 255) & ~(size_t)255)

typedef float f4v __attribute__((ext_vector_type(4)));
typedef __attribute__((ext_vector_type(8))) short bf16x8;
typedef __attribute__((ext_vector_type(4))) float f32x4;
typedef __attribute__((ext_vector_type(4))) unsigned short us4;

__device__ inline void nt_store4(float* p, float4 v) {
  __builtin_nontemporal_store(*(f4v*)&v, (f4v*)p);
}

__device__ inline unsigned short f2bf(float v) {
  unsigned int u = __float_as_uint(v);
  u += 0x7FFF + ((u >> 16) & 1);   // RNE
  return (unsigned short)(u >> 16);
}
__device__ inline float bf2f(unsigned short h) {
  return __uint_as_float(((unsigned int)h) << 16);
}

// ---------------- pack edges (N < 65536) + dst-degree count ----------------
__global__ void k_pack_count(const int* __restrict__ src, const int* __restrict__ dst, int E,
                             unsigned int* __restrict__ packed, int* __restrict__ deg) {
  int e = blockIdx.x * blockDim.x + threadIdx.x;
  if (e < E) {
    int s = src[e];
    int d = dst[e];
    packed[e] = (unsigned int)s | ((unsigned int)d << 16);
    atomicAdd(&deg[d], 1);
  }
}

__global__ void k_dis(const int* __restrict__ deg, float* __restrict__ dis, int N) {
  int i = blockIdx.x * blockDim.x + threadIdx.x;
  if (i < N) dis[i] = rsqrtf((float)(deg[i] + 1));  // +1 self-loop
}

// ---------------- degree histogram (256 bins) ----------------
__global__ void k_hist(const int* __restrict__ deg, int N, int* __restrict__ hist) {
  int i = blockIdx.x * blockDim.x + threadIdx.x;
  if (i < N) atomicAdd(&hist[min(deg[i], 255)], 1);
}

// exclusive scan of 256 bins -> bin cursors (single block, LDS Hillis-Steele)
__global__ __launch_bounds__(256) void k_scan_bins(const int* __restrict__ hist,
                                                   int* __restrict__ bin_cur) {
  __shared__ int buf[256];
  int t = threadIdx.x;
  buf[t] = hist[t];
  __syncthreads();
  for (int off = 1; off < 256; off <<= 1) {
    int v = (t >= off) ? buf[t - off] : 0;
    __syncthreads();
    buf[t] += v;
    __syncthreads();
  }
  bin_cur[t] = (t == 0) ? 0 : buf[t - 1];   // exclusive
}

// scatter nodes into perm in ascending-degree order
__global__ void k_scatter_perm(const int* __restrict__ deg, int N,
                               int* __restrict__ bin_cur, unsigned short* __restrict__ perm) {
  int i = blockIdx.x * blockDim.x + threadIdx.x;
  if (i < N) {
    int b = min(deg[i], 255);
    int pos = atomicAdd(&bin_cur[b], 1);
    perm[pos] = (unsigned short)i;
  }
}

// ---------------- exclusive scan (single block) ----------------
__global__ __launch_bounds__(1024) void k_scan(const int* __restrict__ deg,
                                               int* __restrict__ rowptr,
                                               int* __restrict__ cursor,
                                               int N, int Etot) {
  __shared__ int wsum[16];
  __shared__ int s_carry;
  int tid = threadIdx.x, lane = tid & 63, w = tid >> 6;
  if (tid == 0) { s_carry = 0; rowptr[N] = Etot; }
  __syncthreads();
  for (int base = 0; base < N; base += 4096) {
    int i0 = base + tid * 4;
    int v[4];
    #pragma unroll
    for (int u = 0; u < 4; ++u) {
      int i = i0 + u;
      v[u] = (i < N) ? deg[i] : 0;
    }
    int tsum = v[0] + v[1] + v[2] + v[3];
    int sc = tsum;
    #pragma unroll
    for (int off = 1; off < 64; off <<= 1) {
      int t = __shfl_up(sc, off);
      if (lane >= off) sc += t;
    }
    if (lane == 63) wsum[w] = sc;
    __syncthreads();
    if (w == 0 && lane < 16) {
      int xx = wsum[lane];
      #pragma unroll
      for (int off = 1; off < 16; off <<= 1) {
        int t = __shfl_up(xx, off);
        if (lane >= off) xx += t;
      }
      wsum[lane] = xx;
    }
    __syncthreads();
    int woff = (w == 0) ? 0 : wsum[w - 1];
    int excl = s_carry + woff + (sc - tsum);
    #pragma unroll
    for (int u = 0; u < 4; ++u) {
      int i = i0 + u;
      if (i < N) { rowptr[i] = excl; cursor[i] = excl; }
      excl += v[u];
    }
    __syncthreads();
    if (tid == 0) s_carry += wsum[15];
    __syncthreads();
  }
}

// ---------------- XCD-partitioned CSR fill (r18 proven) ----------------
__global__ __launch_bounds__(256) void k_fill_xcd(const unsigned int* __restrict__ packed,
                                                  int E, int N,
                                                  int* __restrict__ cursor,
                                                  unsigned short* __restrict__ csr16) {
  int bid = blockIdx.x;
  int xcd = bid & 7;
  int tix = ((bid >> 3) << 8) + threadIdx.x;
  int tpx = ((int)(gridDim.x >> 3)) << 8;
  int lo = (int)(((long long)N * xcd) >> 3);
  int hi = (int)(((long long)N * (xcd + 1)) >> 3);
  for (int e = tix; e < E; e += tpx) {
    unsigned int pk = packed[e];
    int d = (int)(pk >> 16);
    if (d >= lo && d < hi) {
      int pos = atomicAdd(&cursor[d], 1);
      csr16[pos] = (unsigned short)(pk & 0xFFFFu);
    }
  }
}

// ---------------- split-bf16 MFMA GEMM, slice-major output (r19 proven) ----------------
#define APAD 40
__global__ __launch_bounds__(256) void k_gemm_mfma_sm(const float* __restrict__ A,
                                                      const float* __restrict__ B,
                                                      const float* __restrict__ dis,
                                                      float* __restrict__ C,
                                                      int M, int Nc, int K) {
  __shared__ unsigned short As_hi[128][APAD];
  __shared__ unsigned short As_lo[128][APAD];
  __shared__ unsigned short Bs_hi[64][APAD];
  __shared__ unsigned short Bs_lo[64][APAD];
  int tid = threadIdx.x;
  int wv = tid >> 6, lane = tid & 63;
  int block_row = blockIdx.x * 128;
  int block_col = blockIdx.y * 64;

  f32x4 acc[2][4] = {};

  for (int k0 = 0; k0 < K; k0 += 32) {
    {
      int row = tid >> 1;
      int grow = block_row + row;
      int qb = (tid & 1) * 16;
      const float* ap = A + (size_t)grow * K + k0 + qb;
      #pragma unroll
      for (int i = 0; i < 4; ++i) {
        float4 v = {0.f, 0.f, 0.f, 0.f};
        if (grow < M) v = *(const float4*)(ap + i * 4);
        us4 h, l;
        h.x = f2bf(v.x); h.y = f2bf(v.y); h.z = f2bf(v.z); h.w = f2bf(v.w);
        l.x = f2bf(v.x - bf2f(h.x)); l.y = f2bf(v.y - bf2f(h.y));
        l.z = f2bf(v.z - bf2f(h.z)); l.w = f2bf(v.w - bf2f(h.w));
        *(us4*)&As_hi[row][qb + i * 4] = h;
        *(us4*)&As_lo[row][qb + i * 4] = l;
      }
    }
    {
      int n = tid & 63;
      int ksb = (tid >> 6) * 8;
      int gn = block_col + n;
      #pragma unroll
      for (int j = 0; j < 8; ++j) {
        float v = B[(size_t)(k0 + ksb + j) * Nc + gn];
        unsigned short h = f2bf(v);
        Bs_hi[n][ksb + j] = h;
        Bs_lo[n][ksb + j] = f2bf(v - bf2f(h));
      }
    }
    __syncthreads();
    int frow = lane & 15;
    int fk = (lane >> 4) * 8;
    bf16x8 ah[2], al[2], bh[4], bl[4];
    #pragma unroll
    for (int rf = 0; rf < 2; ++rf) {
      int r = wv * 32 + rf * 16 + frow;
      ah[rf] = *(const bf16x8*)&As_hi[r][fk];
      al[rf] = *(const bf16x8*)&As_lo[r][fk];
    }
    #pragma unroll
    for (int cf = 0; cf < 4; ++cf) {
      int c = cf * 16 + frow;
      bh[cf] = *(const bf16x8*)&Bs_hi[c][fk];
      bl[cf] = *(const bf16x8*)&Bs_lo[c][fk];
    }
    #pragma unroll
    for (int rf = 0; rf < 2; ++rf)
      #pragma unroll
      for (int cf = 0; cf < 4; ++cf) {
        acc[rf][cf] = __builtin_amdgcn_mfma_f32_16x16x32_bf16(ah[rf], bh[cf], acc[rf][cf], 0, 0, 0);
        acc[rf][cf] = __builtin_amdgcn_mfma_f32_16x16x32_bf16(ah[rf], bl[cf], acc[rf][cf], 0, 0, 0);
        acc[rf][cf] = __builtin_amdgcn_mfma_f32_16x16x32_bf16(al[rf], bh[cf], acc[rf][cf], 0, 0, 0);
      }
    __syncthreads();
  }
  int fcol = lane & 15;
  #pragma unroll
  for (int rf = 0; rf < 2; ++rf) {
    int rbase = block_row + wv * 32 + rf * 16 + (lane >> 4) * 4;
    #pragma unroll
    for (int j = 0; j < 4; ++j) {
      int row = rbase + j;
      if (row < M) {
        float dn = dis[row];
        #pragma unroll
        for (int cf = 0; cf < 4; ++cf) {
          int sl = (block_col >> 4) + cf;
          C[((size_t)sl * M + row) * 16 + fcol] = acc[rf][cf][j] * dn;
        }
      }
    }
  }
}

// ---------------- XCD-pinned sliced aggregation, degree-sorted node permutation ----------------
// Wave walkers get 8 SIMILAR-DEGREE nodes via perm (ascending in-degree):
// max ~= mean -> no masked-iteration waste from degree variance.
template <int FCH, bool OUTSLICE>
__global__ __launch_bounds__(256) void k_agg_xcd(const float* __restrict__ hs,
                                                 const int* __restrict__ rowptr,
                                                 const unsigned short* __restrict__ csr,
                                                 const unsigned short* __restrict__ perm,
                                                 const float* __restrict__ dis,
                                                 const float* __restrict__ bias,
                                                 float* __restrict__ out,
                                                 int N, int do_relu, int phase) {
  int bid = blockIdx.x;
  int xcd = bid & 7;
  int wid = threadIdx.x >> 6;
  int lane = threadIdx.x & 63;
  int sub = lane >> 3;          // walker within wave (0..7)
  int epar = (lane >> 2) & 1;   // edge-parallel 0/1
  int c2 = lane & 3;            // float4 chunk of 16-ch row
  int wix = ((bid >> 3) << 2) + wid;
  int wpx = ((int)(gridDim.x >> 3)) << 2;
  int nchunk = (N + 7) >> 3;

  int s = xcd + (phase << 3);
  const float* in = hs + (size_t)s * N * 16;
  for (int ch = wix; ch < nchunk; ch += wpx) {
    int pidx = (ch << 3) + sub;
    bool valid = pidx < N;
    int node = 0;
    int b0 = 0, e0 = 0;
    if (valid) {
      node = perm[pidx];
      b0 = rowptr[node];
      e0 = rowptr[node + 1];
    }
    float4 acc = {0.f, 0.f, 0.f, 0.f};
    int j = b0 + epar;
    for (; j + 6 < e0; j += 8) {
      int i0 = csr[j];     int i1 = csr[j + 2];
      int i2 = csr[j + 4]; int i3 = csr[j + 6];
      float4 v0 = *(const float4*)(in + ((size_t)i0 << 4) + (c2 << 2));
      float4 v1 = *(const float4*)(in + ((size_t)i1 << 4) + (c2 << 2));
      float4 v2 = *(const float4*)(in + ((size_t)i2 << 4) + (c2 << 2));
      float4 v3 = *(const float4*)(in + ((size_t)i3 << 4) + (c2 << 2));
      acc.x += (v0.x + v1.x) + (v2.x + v3.x);
      acc.y += (v0.y + v1.y) + (v2.y + v3.y);
      acc.z += (v0.z + v1.z) + (v2.z + v3.z);
      acc.w += (v0.w + v1.w) + (v2.w + v3.w);
    }
    for (; j < e0; j += 2) {
      int idx = csr[j];
      float4 v = *(const float4*)(in + ((size_t)idx << 4) + (c2 << 2));
      acc.x += v.x; acc.y += v.y; acc.z += v.z; acc.w += v.w;
    }
    acc.x += __shfl_xor(acc.x, 4);
    acc.y += __shfl_xor(acc.y, 4);
    acc.z += __shfl_xor(acc.z, 4);
    acc.w += __shfl_xor(acc.w, 4);
    if (valid && epar == 0) {
      float4 self = *(const float4*)(in + ((size_t)node << 4) + (c2 << 2));
      float dn = dis[node];
      int col = (s << 4) + (c2 << 2);
      float4 bv = *(const float4*)(bias + col);
      float4 r;
      r.x = (acc.x + self.x) * dn + bv.x;
      r.y = (acc.y + self.y) * dn + bv.y;
      r.z = (acc.z + self.z) * dn + bv.z;
      r.w = (acc.w + self.w) * dn + bv.w;
      if (do_relu) {
        r.x = fmaxf(r.x, 0.f); r.y = fmaxf(r.y, 0.f);
        r.z = fmaxf(r.z, 0.f); r.w = fmaxf(r.w, 0.f);
      }
      if (OUTSLICE)
        nt_store4(out + (size_t)s * N * 16 + ((size_t)node << 4) + (c2 << 2), r);
      else
        nt_store4(out + (size_t)node * FCH + col, r);
    }
  }
}

// ---------------- XCD-pinned decode, coalesced 4-lane rows, 64 edges/wave-iter ----------------
__global__ __launch_bounds__(256) void k_decode_xcd4(const float* __restrict__ z,
                                                     const unsigned int* __restrict__ packed,
                                                     float* __restrict__ partial,
                                                     int E, int N) {
  int bid = blockIdx.x;
  int xcd = bid & 7;
  int wid = threadIdx.x >> 6;
  int lane = threadIdx.x & 63;
  int c2 = lane & 3;
  int sub = lane >> 2;
  int wix = ((bid >> 3) << 2) + wid;
  int wpx = ((int)(gridDim.x >> 3)) << 2;
  const float* zc = z + (size_t)xcd * N * 16;
  float* pp = partial + (size_t)xcd * E;

  for (int e0 = wix * 64; e0 < E; e0 += wpx * 64) {
    float pv[4];
    int ev[4];
    #pragma unroll
    for (int q = 0; q < 4; ++q) {
      int e = e0 + q * 16 + sub;
      ev[q] = e;
      pv[q] = 0.f;
      if (e < E) {
        unsigned int pk = packed[e];
        int a = (int)(pk & 0xFFFFu), d = (int)(pk >> 16);
        float4 za = *(const float4*)(zc + ((size_t)a << 4) + (c2 << 2));
        float4 zb = *(const float4*)(zc + ((size_t)d << 4) + (c2 << 2));
        pv[q] = za.x * zb.x + za.y * zb.y + za.z * zb.z + za.w * zb.w;
      }
    }
    #pragma unroll
    for (int q = 0; q < 4; ++q) {
      pv[q] += __shfl_xor(pv[q], 1);
      pv[q] += __shfl_xor(pv[q], 2);
    }
    if (c2 == 0) {
      #pragma unroll
      for (int q = 0; q < 4; ++q)
        if (ev[q] < E) pp[ev[q]] = pv[q];
    }
  }
}

// ---------------- dreduce: float4 over edges ----------------
__global__ void k_dreduce4(const float* __restrict__ partial, float* __restrict__ out, int E) {
  int q = blockIdx.x * 256 + threadIdx.x;
  int e = q << 2;
  if (e >= E) return;
  if (e + 4 <= E) {
    float4 s = *(const float4*)(partial + e);
    #pragma unroll
    for (int k = 1; k < 8; ++k) {
      float4 t = *(const float4*)(partial + (size_t)k * E + e);
      s.x += t.x; s.y += t.y; s.z += t.z; s.w += t.w;
    }
    *(float4*)(out + e) = s;
  } else {
    for (int i = e; i < E; ++i) {
      float s = 0.f;
      #pragma unroll
      for (int k = 0; k < 8; ++k) s += partial[(size_t)k * E + i];
      out[i] = s;
    }
  }
}

extern "C" void kernel_launch(void* const* d_in, const int* in_sizes, int n_in,
                              void* d_out, int out_size, void* d_ws, size_t ws_size,
                              hipStream_t stream) {
  const float* x  = (const float*)d_in[0];
  const int* eidx = (const int*)d_in[1];
  const float* W1 = (const float*)d_in[2];
  const float* b1 = (const float*)d_in[3];
  const float* W2 = (const float*)d_in[4];
  const float* b2 = (const float*)d_in[5];
  float* out = (float*)d_out;

  const int IN_CH = 256, HID = 256, OUT_CH = 128;
  const int N = in_sizes[0] / IN_CH;
  const int E = in_sizes[1] / 2;
  const int* esrc = eidx;
  const int* edst = eidx + E;

  char* p = (char*)d_ws;
  auto alloc = [&](size_t bytes) -> char* { char* r = p; p += WS_ALIGN(bytes); return r; };
  int*   deg    = (int*)  alloc(sizeof(int) * N);
  float* dis    = (float*)alloc(sizeof(float) * N);
  int*   rowptr = (int*)  alloc(sizeof(int) * (N + 1));
  int*   cursor = (int*)  alloc(sizeof(int) * N);
  int*   hist   = (int*)  alloc(sizeof(int) * 256);
  int*   bin_cur= (int*)  alloc(sizeof(int) * 256);
  unsigned short* perm  = (unsigned short*)alloc(sizeof(unsigned short) * N);
  unsigned short* csr16 = (unsigned short*)alloc(sizeof(unsigned short) * (size_t)E);
  unsigned int*   packed = (unsigned int*) alloc(sizeof(unsigned int) * (size_t)E);
  float* bufA   = (float*)alloc(sizeof(float) * (size_t)N * HID);  // h1s / h2s; reused as decode partials
  float* bufB   = (float*)alloc(sizeof(float) * (size_t)N * HID);  // z1 (row-major) / z2 (slice-major)

  const int T = 256;
  const int PG = 2048;  // persistent grid: 8 blocks/CU, 256 blocks/XCD

  hipMemsetAsync(deg, 0, sizeof(int) * N, stream);
  hipMemsetAsync(hist, 0, sizeof(int) * 256, stream);
  hipLaunchKernelGGL(k_pack_count, dim3((E + T - 1) / T), dim3(T), 0, stream,
                     esrc, edst, E, packed, deg);
  hipLaunchKernelGGL(k_dis, dim3((N + T - 1) / T), dim3(T), 0, stream, deg, dis, N);
  hipLaunchKernelGGL(k_hist, dim3((N + T - 1) / T), dim3(T), 0, stream, deg, N, hist);
  hipLaunchKernelGGL(k_scan_bins, dim3(1), dim3(256), 0, stream, hist, bin_cur);
  hipLaunchKernelGGL(k_scatter_perm, dim3((N + T - 1) / T), dim3(T), 0, stream,
                     deg, N, bin_cur, perm);
  hipLaunchKernelGGL(k_scan, dim3(1), dim3(1024), 0, stream, deg, rowptr, cursor, N, E);
  hipLaunchKernelGGL(k_fill_xcd, dim3(PG), dim3(T), 0, stream, packed, E, N, cursor, csr16);

  // conv1: h1s = (x @ W1)*dis[row] slice-major (MFMA split-bf16); z1 row-major
  dim3 g1((N + 127) / 128, HID / 64);
  hipLaunchKernelGGL(k_gemm_mfma_sm, g1, dim3(256), 0, stream, x, W1, dis, bufA, N, HID, IN_CH);
  hipLaunchKernelGGL((k_agg_xcd<256, false>), dim3(PG), dim3(256), 0, stream,
                     bufA, rowptr, csr16, perm, dis, b1, bufB, N, 1, 0);
  hipLaunchKernelGGL((k_agg_xcd<256, false>), dim3(PG), dim3(256), 0, stream,
                     bufA, rowptr, csr16, perm, dis, b1, bufB, N, 1, 1);

  // conv2: h2s = (z1 @ W2)*dis[row] slice-major; z2 slice-major
  dim3 g2((N + 127) / 128, OUT_CH / 64);
  hipLaunchKernelGGL(k_gemm_mfma_sm, g2, dim3(256), 0, stream, bufB, W2, dis, bufA, N, OUT_CH, HID);
  hipLaunchKernelGGL((k_agg_xcd<128, true>), dim3(PG), dim3(256), 0, stream,
                     bufA, rowptr, csr16, perm, dis, b2, bufB, N, 0, 0);

  // decode: per-XCD slice partial dots into bufA (h2s dead), then reduce
  hipLaunchKernelGGL(k_decode_xcd4, dim3(PG), dim3(256), 0, stream,
                     bufB, packed, bufA, E, N);
  hipLaunchKernelGGL(k_dreduce4, dim3((E / 4 + 255) / 256), dim3(256), 0, stream,
                     bufA, out, E);
}

// Round 21
// 626.007 us; speedup vs baseline: 1.3951x; 1.3951x over previous
//
#include <hip/hip_runtime.h>

#define WS_ALIGN(x) (((x) + 255) & ~(size_t)255)

typedef float f4v __attribute__((ext_vector_type(4)));
typedef __attribute__((ext_vector_type(8))) short bf16x8;
typedef __attribute__((ext_vector_type(4))) float f32x4;
typedef __attribute__((ext_vector_type(4))) unsigned short us4;

__device__ inline void nt_store4(float* p, float4 v) {
  __builtin_nontemporal_store(*(f4v*)&v, (f4v*)p);
}

__device__ inline unsigned short f2bf(float v) {
  unsigned int u = __float_as_uint(v);
  u += 0x7FFF + ((u >> 16) & 1);   // RNE
  return (unsigned short)(u >> 16);
}
__device__ inline float bf2f(unsigned short h) {
  return __uint_as_float(((unsigned int)h) << 16);
}

// ---------------- pack edges (N < 65536) + dst-degree count ----------------
__global__ void k_pack_count(const int* __restrict__ src, const int* __restrict__ dst, int E,
                             unsigned int* __restrict__ packed, int* __restrict__ deg) {
  int e = blockIdx.x * blockDim.x + threadIdx.x;
  if (e < E) {
    int s = src[e];
    int d = dst[e];
    packed[e] = (unsigned int)s | ((unsigned int)d << 16);
    atomicAdd(&deg[d], 1);
  }
}

__global__ void k_dis(const int* __restrict__ deg, float* __restrict__ dis, int N) {
  int i = blockIdx.x * blockDim.x + threadIdx.x;
  if (i < N) dis[i] = rsqrtf((float)(deg[i] + 1));  // +1 self-loop
}

// ---------------- exclusive scan (single block) ----------------
__global__ __launch_bounds__(1024) void k_scan(const int* __restrict__ deg,
                                               int* __restrict__ rowptr,
                                               int* __restrict__ cursor,
                                               int N, int Etot) {
  __shared__ int wsum[16];
  __shared__ int s_carry;
  int tid = threadIdx.x, lane = tid & 63, w = tid >> 6;
  if (tid == 0) { s_carry = 0; rowptr[N] = Etot; }
  __syncthreads();
  for (int base = 0; base < N; base += 4096) {
    int i0 = base + tid * 4;
    int v[4];
    #pragma unroll
    for (int u = 0; u < 4; ++u) {
      int i = i0 + u;
      v[u] = (i < N) ? deg[i] : 0;
    }
    int tsum = v[0] + v[1] + v[2] + v[3];
    int sc = tsum;
    #pragma unroll
    for (int off = 1; off < 64; off <<= 1) {
      int t = __shfl_up(sc, off);
      if (lane >= off) sc += t;
    }
    if (lane == 63) wsum[w] = sc;
    __syncthreads();
    if (w == 0 && lane < 16) {
      int xx = wsum[lane];
      #pragma unroll
      for (int off = 1; off < 16; off <<= 1) {
        int t = __shfl_up(xx, off);
        if (lane >= off) xx += t;
      }
      wsum[lane] = xx;
    }
    __syncthreads();
    int woff = (w == 0) ? 0 : wsum[w - 1];
    int excl = s_carry + woff + (sc - tsum);
    #pragma unroll
    for (int u = 0; u < 4; ++u) {
      int i = i0 + u;
      if (i < N) { rowptr[i] = excl; cursor[i] = excl; }
      excl += v[u];
    }
    __syncthreads();
    if (tid == 0) s_carry += wsum[15];
    __syncthreads();
  }
}

// ---------------- XCD-partitioned CSR fill (r18 proven) ----------------
__global__ __launch_bounds__(256) void k_fill_xcd(const unsigned int* __restrict__ packed,
                                                  int E, int N,
                                                  int* __restrict__ cursor,
                                                  unsigned short* __restrict__ csr16) {
  int bid = blockIdx.x;
  int xcd = bid & 7;
  int tix = ((bid >> 3) << 8) + threadIdx.x;
  int tpx = ((int)(gridDim.x >> 3)) << 8;
  int lo = (int)(((long long)N * xcd) >> 3);
  int hi = (int)(((long long)N * (xcd + 1)) >> 3);
  for (int e = tix; e < E; e += tpx) {
    unsigned int pk = packed[e];
    int d = (int)(pk >> 16);
    if (d >= lo && d < hi) {
      int pos = atomicAdd(&cursor[d], 1);
      csr16[pos] = (unsigned short)(pk & 0xFFFFu);
    }
  }
}

// ---------------- split-bf16 MFMA GEMM, slice-major output (r19 proven) ----------------
#define APAD 40
__global__ __launch_bounds__(256) void k_gemm_mfma_sm(const float* __restrict__ A,
                                                      const float* __restrict__ B,
                                                      const float* __restrict__ dis,
                                                      float* __restrict__ C,
                                                      int M, int Nc, int K) {
  __shared__ unsigned short As_hi[128][APAD];
  __shared__ unsigned short As_lo[128][APAD];
  __shared__ unsigned short Bs_hi[64][APAD];
  __shared__ unsigned short Bs_lo[64][APAD];
  int tid = threadIdx.x;
  int wv = tid >> 6, lane = tid & 63;
  int block_row = blockIdx.x * 128;
  int block_col = blockIdx.y * 64;

  f32x4 acc[2][4] = {};

  for (int k0 = 0; k0 < K; k0 += 32) {
    {
      int row = tid >> 1;
      int grow = block_row + row;
      int qb = (tid & 1) * 16;
      const float* ap = A + (size_t)grow * K + k0 + qb;
      #pragma unroll
      for (int i = 0; i < 4; ++i) {
        float4 v = {0.f, 0.f, 0.f, 0.f};
        if (grow < M) v = *(const float4*)(ap + i * 4);
        us4 h, l;
        h.x = f2bf(v.x); h.y = f2bf(v.y); h.z = f2bf(v.z); h.w = f2bf(v.w);
        l.x = f2bf(v.x - bf2f(h.x)); l.y = f2bf(v.y - bf2f(h.y));
        l.z = f2bf(v.z - bf2f(h.z)); l.w = f2bf(v.w - bf2f(h.w));
        *(us4*)&As_hi[row][qb + i * 4] = h;
        *(us4*)&As_lo[row][qb + i * 4] = l;
      }
    }
    {
      int n = tid & 63;
      int ksb = (tid >> 6) * 8;
      int gn = block_col + n;
      #pragma unroll
      for (int j = 0; j < 8; ++j) {
        float v = B[(size_t)(k0 + ksb + j) * Nc + gn];
        unsigned short h = f2bf(v);
        Bs_hi[n][ksb + j] = h;
        Bs_lo[n][ksb + j] = f2bf(v - bf2f(h));
      }
    }
    __syncthreads();
    int frow = lane & 15;
    int fk = (lane >> 4) * 8;
    bf16x8 ah[2], al[2], bh[4], bl[4];
    #pragma unroll
    for (int rf = 0; rf < 2; ++rf) {
      int r = wv * 32 + rf * 16 + frow;
      ah[rf] = *(const bf16x8*)&As_hi[r][fk];
      al[rf] = *(const bf16x8*)&As_lo[r][fk];
    }
    #pragma unroll
    for (int cf = 0; cf < 4; ++cf) {
      int c = cf * 16 + frow;
      bh[cf] = *(const bf16x8*)&Bs_hi[c][fk];
      bl[cf] = *(const bf16x8*)&Bs_lo[c][fk];
    }
    #pragma unroll
    for (int rf = 0; rf < 2; ++rf)
      #pragma unroll
      for (int cf = 0; cf < 4; ++cf) {
        acc[rf][cf] = __builtin_amdgcn_mfma_f32_16x16x32_bf16(ah[rf], bh[cf], acc[rf][cf], 0, 0, 0);
        acc[rf][cf] = __builtin_amdgcn_mfma_f32_16x16x32_bf16(ah[rf], bl[cf], acc[rf][cf], 0, 0, 0);
        acc[rf][cf] = __builtin_amdgcn_mfma_f32_16x16x32_bf16(al[rf], bh[cf], acc[rf][cf], 0, 0, 0);
      }
    __syncthreads();
  }
  int fcol = lane & 15;
  #pragma unroll
  for (int rf = 0; rf < 2; ++rf) {
    int rbase = block_row + wv * 32 + rf * 16 + (lane >> 4) * 4;
    #pragma unroll
    for (int j = 0; j < 4; ++j) {
      int row = rbase + j;
      if (row < M) {
        float dn = dis[row];
        #pragma unroll
        for (int cf = 0; cf < 4; ++cf) {
          int sl = (block_col >> 4) + cf;
          C[((size_t)sl * M + row) * 16 + fcol] = acc[rf][cf][j] * dn;
        }
      }
    }
  }
}

// ---------------- XCD-pinned sliced aggregation (ONE phase per launch) — r16/r19 proven ----------------
template <int FCH, bool OUTSLICE>
__global__ __launch_bounds__(256) void k_agg_xcd(const float* __restrict__ hs,
                                                 const int* __restrict__ rowptr,
                                                 const unsigned short* __restrict__ csr,
                                                 const float* __restrict__ dis,
                                                 const float* __restrict__ bias,
                                                 float* __restrict__ out,
                                                 int N, int do_relu, int phase) {
  int bid = blockIdx.x;
  int xcd = bid & 7;
  int wid = threadIdx.x >> 6;
  int lane = threadIdx.x & 63;
  int sub = lane >> 3;          // node within chunk (0..7)
  int epar = (lane >> 2) & 1;   // edge-parallel 0/1
  int c2 = lane & 3;            // float4 chunk of 16-ch row
  int wix = ((bid >> 3) << 2) + wid;
  int wpx = ((int)(gridDim.x >> 3)) << 2;
  int nchunk = (N + 7) >> 3;

  int s = xcd + (phase << 3);
  const float* in = hs + (size_t)s * N * 16;
  for (int ch = wix; ch < nchunk; ch += wpx) {
    int node = (ch << 3) + sub;
    bool valid = node < N;
    int b0 = 0, e0 = 0;
    if (valid) { b0 = rowptr[node]; e0 = rowptr[node + 1]; }
    float4 acc = {0.f, 0.f, 0.f, 0.f};
    int j = b0 + epar;
    for (; j + 6 < e0; j += 8) {
      int i0 = csr[j];     int i1 = csr[j + 2];
      int i2 = csr[j + 4]; int i3 = csr[j + 6];
      float4 v0 = *(const float4*)(in + ((size_t)i0 << 4) + (c2 << 2));
      float4 v1 = *(const float4*)(in + ((size_t)i1 << 4) + (c2 << 2));
      float4 v2 = *(const float4*)(in + ((size_t)i2 << 4) + (c2 << 2));
      float4 v3 = *(const float4*)(in + ((size_t)i3 << 4) + (c2 << 2));
      acc.x += (v0.x + v1.x) + (v2.x + v3.x);
      acc.y += (v0.y + v1.y) + (v2.y + v3.y);
      acc.z += (v0.z + v1.z) + (v2.z + v3.z);
      acc.w += (v0.w + v1.w) + (v2.w + v3.w);
    }
    for (; j < e0; j += 2) {
      int idx = csr[j];
      float4 v = *(const float4*)(in + ((size_t)idx << 4) + (c2 << 2));
      acc.x += v.x; acc.y += v.y; acc.z += v.z; acc.w += v.w;
    }
    acc.x += __shfl_xor(acc.x, 4);
    acc.y += __shfl_xor(acc.y, 4);
    acc.z += __shfl_xor(acc.z, 4);
    acc.w += __shfl_xor(acc.w, 4);
    if (valid && epar == 0) {
      float4 self = *(const float4*)(in + ((size_t)node << 4) + (c2 << 2));
      float dn = dis[node];
      int col = (s << 4) + (c2 << 2);
      float4 bv = *(const float4*)(bias + col);
      float4 r;
      r.x = (acc.x + self.x) * dn + bv.x;
      r.y = (acc.y + self.y) * dn + bv.y;
      r.z = (acc.z + self.z) * dn + bv.z;
      r.w = (acc.w + self.w) * dn + bv.w;
      if (do_relu) {
        r.x = fmaxf(r.x, 0.f); r.y = fmaxf(r.y, 0.f);
        r.z = fmaxf(r.z, 0.f); r.w = fmaxf(r.w, 0.f);
      }
      if (OUTSLICE)
        nt_store4(out + (size_t)s * N * 16 + ((size_t)node << 4) + (c2 << 2), r);
      else
        nt_store4(out + (size_t)node * FCH + col, r);
    }
  }
}

// ---------------- XCD-pinned decode, coalesced 4-lane rows, 64 edges/wave-iter ----------------
__global__ __launch_bounds__(256) void k_decode_xcd4(const float* __restrict__ z,
                                                     const unsigned int* __restrict__ packed,
                                                     float* __restrict__ partial,
                                                     int E, int N) {
  int bid = blockIdx.x;
  int xcd = bid & 7;
  int wid = threadIdx.x >> 6;
  int lane = threadIdx.x & 63;
  int c2 = lane & 3;
  int sub = lane >> 2;
  int wix = ((bid >> 3) << 2) + wid;
  int wpx = ((int)(gridDim.x >> 3)) << 2;
  const float* zc = z + (size_t)xcd * N * 16;
  float* pp = partial + (size_t)xcd * E;

  for (int e0 = wix * 64; e0 < E; e0 += wpx * 64) {
    float pv[4];
    int ev[4];
    #pragma unroll
    for (int q = 0; q < 4; ++q) {
      int e = e0 + q * 16 + sub;
      ev[q] = e;
      pv[q] = 0.f;
      if (e < E) {
        unsigned int pk = packed[e];
        int a = (int)(pk & 0xFFFFu), d = (int)(pk >> 16);
        float4 za = *(const float4*)(zc + ((size_t)a << 4) + (c2 << 2));
        float4 zb = *(const float4*)(zc + ((size_t)d << 4) + (c2 << 2));
        pv[q] = za.x * zb.x + za.y * zb.y + za.z * zb.z + za.w * zb.w;
      }
    }
    #pragma unroll
    for (int q = 0; q < 4; ++q) {
      pv[q] += __shfl_xor(pv[q], 1);
      pv[q] += __shfl_xor(pv[q], 2);
    }
    if (c2 == 0) {
      #pragma unroll
      for (int q = 0; q < 4; ++q)
        if (ev[q] < E) pp[ev[q]] = pv[q];
    }
  }
}

// ---------------- dreduce: float4 over edges ----------------
__global__ void k_dreduce4(const float* __restrict__ partial, float* __restrict__ out, int E) {
  int q = blockIdx.x * 256 + threadIdx.x;
  int e = q << 2;
  if (e >= E) return;
  if (e + 4 <= E) {
    float4 s = *(const float4*)(partial + e);
    #pragma unroll
    for (int k = 1; k < 8; ++k) {
      float4 t = *(const float4*)(partial + (size_t)k * E + e);
      s.x += t.x; s.y += t.y; s.z += t.z; s.w += t.w;
    }
    *(float4*)(out + e) = s;
  } else {
    for (int i = e; i < E; ++i) {
      float s = 0.f;
      #pragma unroll
      for (int k = 0; k < 8; ++k) s += partial[(size_t)k * E + i];
      out[i] = s;
    }
  }
}

extern "C" void kernel_launch(void* const* d_in, const int* in_sizes, int n_in,
                              void* d_out, int out_size, void* d_ws, size_t ws_size,
                              hipStream_t stream) {
  const float* x  = (const float*)d_in[0];
  const int* eidx = (const int*)d_in[1];
  const float* W1 = (const float*)d_in[2];
  const float* b1 = (const float*)d_in[3];
  const float* W2 = (const float*)d_in[4];
  const float* b2 = (const float*)d_in[5];
  float* out = (float*)d_out;

  const int IN_CH = 256, HID = 256, OUT_CH = 128;
  const int N = in_sizes[0] / IN_CH;
  const int E = in_sizes[1] / 2;
  const int* esrc = eidx;
  const int* edst = eidx + E;

  char* p = (char*)d_ws;
  auto alloc = [&](size_t bytes) -> char* { char* r = p; p += WS_ALIGN(bytes); return r; };
  int*   deg    = (int*)  alloc(sizeof(int) * N);
  float* dis    = (float*)alloc(sizeof(float) * N);
  int*   rowptr = (int*)  alloc(sizeof(int) * (N + 1));
  int*   cursor = (int*)  alloc(sizeof(int) * N);
  unsigned short* csr16 = (unsigned short*)alloc(sizeof(unsigned short) * (size_t)E);
  unsigned int*   packed = (unsigned int*) alloc(sizeof(unsigned int) * (size_t)E);
  float* bufA   = (float*)alloc(sizeof(float) * (size_t)N * HID);  // h1s / h2s; reused as decode partials
  float* bufB   = (float*)alloc(sizeof(float) * (size_t)N * HID);  // z1 (row-major) / z2 (slice-major)

  const int T = 256;
  const int PG = 2048;  // persistent grid: 8 blocks/CU, 256 blocks/XCD

  hipMemsetAsync(deg, 0, sizeof(int) * N, stream);
  hipLaunchKernelGGL(k_pack_count, dim3((E + T - 1) / T), dim3(T), 0, stream,
                     esrc, edst, E, packed, deg);
  hipLaunchKernelGGL(k_dis, dim3((N + T - 1) / T), dim3(T), 0, stream, deg, dis, N);
  hipLaunchKernelGGL(k_scan, dim3(1), dim3(1024), 0, stream, deg, rowptr, cursor, N, E);
  hipLaunchKernelGGL(k_fill_xcd, dim3(PG), dim3(T), 0, stream, packed, E, N, cursor, csr16);

  // conv1: h1s = (x @ W1)*dis[row] slice-major (MFMA split-bf16); z1 row-major
  dim3 g1((N + 127) / 128, HID / 64);
  hipLaunchKernelGGL(k_gemm_mfma_sm, g1, dim3(256), 0, stream, x, W1, dis, bufA, N, HID, IN_CH);
  hipLaunchKernelGGL((k_agg_xcd<256, false>), dim3(PG), dim3(256), 0, stream,
                     bufA, rowptr, csr16, dis, b1, bufB, N, 1, 0);
  hipLaunchKernelGGL((k_agg_xcd<256, false>), dim3(PG), dim3(256), 0, stream,
                     bufA, rowptr, csr16, dis, b1, bufB, N, 1, 1);

  // conv2: h2s = (z1 @ W2)*dis[row] slice-major; z2 slice-major
  dim3 g2((N + 127) / 128, OUT_CH / 64);
  hipLaunchKernelGGL(k_gemm_mfma_sm, g2, dim3(256), 0, stream, bufB, W2, dis, bufA, N, OUT_CH, HID);
  hipLaunchKernelGGL((k_agg_xcd<128, true>), dim3(PG), dim3(256), 0, stream,
                     bufA, rowptr, csr16, dis, b2, bufB, N, 0, 0);

  // decode: per-XCD slice partial dots into bufA (h2s dead), then reduce
  hipLaunchKernelGGL(k_decode_xcd4, dim3(PG), dim3(256), 0, stream,
                     bufB, packed, bufA, E, N);
  hipLaunchKernelGGL(k_dreduce4, dim3((E / 4 + 255) / 256), dim3(256), 0, stream,
                     bufA, out, E);
}